// Round 1
// baseline (386.886 us; speedup 1.0000x reference)
//
#include <hip/hip_runtime.h>
#include <math.h>

#define BLOCK 1024
#define NWAVES (BLOCK / 64)
#define CAND_CAP 8192

__device__ __forceinline__ float waveReduceMax(float v) {
#pragma unroll
    for (int off = 32; off > 0; off >>= 1)
        v = fmaxf(v, __shfl_down(v, off, 64));
    return v;
}
__device__ __forceinline__ float waveReduceSum(float v) {
#pragma unroll
    for (int off = 32; off > 0; off >>= 1)
        v += __shfl_down(v, off, 64);
    return v;
}

// One block per row. Row cached in registers (8 x float4 / thread @ 1024 thr
// covers d <= 32768). Candidates (x' >= -1, i.e. x >= rowmax-2) compacted to
// LDS; wave 0 bisects f(tau)=sum max(x'-tau,0)^2 = 1 then closed-form solves
// on the identified support (same formula as the reference's sorted algo).
__global__ __launch_bounds__(BLOCK, 8) void tsallis15_kernel(
    const float* __restrict__ x, const int* __restrict__ tgt,
    float* __restrict__ out, int n, int d, float inv_n)
{
    __shared__ float s_cand[CAND_CAP];
    __shared__ float s_red[NWAVES];
    __shared__ int   s_cnt;
    __shared__ float s_bcast;

    const int row  = blockIdx.x;
    const int t    = threadIdx.x;
    const int lane = t & 63;
    const int wave = t >> 6;
    const float* __restrict__ xr = x + (size_t)row * (size_t)d;

    if (t == 0) s_cnt = 0;

    // ---- single HBM pass: load row into registers ----
    float4 r[8];
#pragma unroll
    for (int i = 0; i < 8; ++i) {
        int e = (i * BLOCK + t) * 4;
        if (e + 4 <= d) {
            r[i] = *reinterpret_cast<const float4*>(xr + e);
        } else {
            float4 v = make_float4(-INFINITY, -INFINITY, -INFINITY, -INFINITY);
            if (e < d)     v.x = xr[e];
            if (e + 1 < d) v.y = xr[e + 1];
            if (e + 2 < d) v.z = xr[e + 2];
            r[i] = v;
        }
    }

    // ---- block max ----
    float m = -INFINITY;
#pragma unroll
    for (int i = 0; i < 8; ++i)
        m = fmaxf(m, fmaxf(fmaxf(r[i].x, r[i].y), fmaxf(r[i].z, r[i].w)));
    m = waveReduceMax(m);
    if (lane == 0) s_red[wave] = m;
    __syncthreads();
    if (wave == 0) {
        float v = (lane < NWAVES) ? s_red[lane] : -INFINITY;
        v = waveReduceMax(v);
        if (lane == 0) s_bcast = v;
    }
    __syncthreads();
    const float rowmax = s_bcast;

    // ---- candidate filter: x >= rowmax - 2  <=>  x' = (x-rowmax)/2 >= -1 ----
    const float thr = rowmax - 2.0f;
#pragma unroll
    for (int i = 0; i < 8; ++i) {
        float vals[4] = { r[i].x, r[i].y, r[i].z, r[i].w };
#pragma unroll
        for (int c = 0; c < 4; ++c) {
            float v = vals[c];
            if (v >= thr) {
                int idx = atomicAdd(&s_cnt, 1);
                if (idx < CAND_CAP) s_cand[idx] = (v - rowmax) * 0.5f;
            }
        }
    }
    __syncthreads();

    // ---- wave 0: root-find + loss terms on the tiny candidate set ----
    if (wave == 0) {
        const int k = min(s_cnt, CAND_CAP);

        // bisection on tau in [-1, 0]; f is monotone decreasing, f(-1)>=1>=f(0)
        float lo = -1.0f, hi = 0.0f;
        for (int it = 0; it < 22; ++it) {
            float tau = 0.5f * (lo + hi);
            float local = 0.0f;
            for (int j = lane; j < k; j += 64) {
                float u = s_cand[j] - tau;
                if (u > 0.0f) local += u * u;
            }
            float tot = waveReduceSum(local);
            tot = __shfl(tot, 0, 64);           // all lanes agree
            if (tot >= 1.0f) lo = tau; else hi = tau;
        }
        const float tau_b = 0.5f * (lo + hi);

        // exact closed form on the identified support:
        //   tau* = mean - sqrt((1 - ss)/k)   (reference's sorted-cumsum formula)
        float s1 = 0.0f, s2 = 0.0f, sc = 0.0f;
        for (int j = lane; j < k; j += 64) {
            float u = s_cand[j];
            if (u > tau_b) { s1 += u; s2 += u * u; sc += 1.0f; }
        }
        s1 = waveReduceSum(s1); s1 = __shfl(s1, 0, 64);
        s2 = waveReduceSum(s2); s2 = __shfl(s2, 0, 64);
        sc = waveReduceSum(sc); sc = __shfl(sc, 0, 64);
        float mean  = s1 / sc;
        float ss    = s2 - s1 * mean;           // sum of squared deviations
        float delta = (1.0f - ss) / sc;
        if (delta < 0.0f) delta = 0.0f;
        const float tau_star = mean - sqrtf(delta);

        // loss terms: sum p^{3/2} = sum u^3, dot(p, x_orig) with x_orig = 2x'+max
        float p32 = 0.0f, dot = 0.0f;
        for (int j = lane; j < k; j += 64) {
            float u = s_cand[j] - tau_star;
            if (u > 0.0f) {
                float p = u * u;
                p32 += p * u;
                dot += p * (2.0f * s_cand[j] + rowmax);
            }
        }
        p32 = waveReduceSum(p32);
        dot = waveReduceSum(dot);
        if (lane == 0) {
            float xt   = xr[tgt[row]];
            float loss = (1.0f - p32) * (4.0f / 3.0f) + dot - xt;
            atomicAdd(out, loss * inv_n);
        }
    }
}

extern "C" void kernel_launch(void* const* d_in, const int* in_sizes, int n_in,
                              void* d_out, int out_size, void* d_ws, size_t ws_size,
                              hipStream_t stream) {
    const float* x   = (const float*)d_in[0];
    const int*   tgt = (const int*)d_in[1];
    float*       out = (float*)d_out;

    const int n = in_sizes[1];
    const int d = in_sizes[0] / n;

    hipMemsetAsync(out, 0, (size_t)out_size * sizeof(float), stream);
    tsallis15_kernel<<<n, BLOCK, 0, stream>>>(x, tgt, out, n, d, 1.0f / (float)n);
}

// Round 2
// 373.868 us; speedup vs baseline: 1.0348x; 1.0348x over previous
//
#include <hip/hip_runtime.h>
#include <math.h>

#define BLOCK 1024
#define NWAVES (BLOCK / 64)
#define CAND_CAP 6144     // LDS candidate buffer (24 KB)
#define NREG 12           // wave0 register-resident candidates: 64*12 = 768

__device__ __forceinline__ float waveReduceMax(float v) {
#pragma unroll
    for (int off = 32; off > 0; off >>= 1)
        v = fmaxf(v, __shfl_down(v, off, 64));
    return v;
}
__device__ __forceinline__ float waveReduceSum(float v) {
#pragma unroll
    for (int off = 32; off > 0; off >>= 1)
        v += __shfl_down(v, off, 64);
    return v;
}

// One block per row; row cached in registers (8 x float4 / thread @ 1024 thr
// covers d <= 32768). launch_bounds(1024,4) => 128 VGPR budget: r[8] (32 regs)
// cannot spill. Candidates (x >= rowmax-2, i.e. u=(x-max)/2 >= -1 >= tau*) are
// compacted to LDS via per-wave ballot (1 atomic per wave-group, not per hit).
// Wave 0 hoists candidates into registers and runs 18 bisection steps on
// f(tau)=sum max(u-tau,0)^2 (monotone; bracket [-1,0]), then the exact
// closed-form tau* = mean - sqrt((1-ss)/k) on the identified support —
// identical to the reference's sorted-cumsum formula.
__global__ __launch_bounds__(BLOCK, 4) void tsallis15_kernel(
    const float* __restrict__ x, const int* __restrict__ tgt,
    float* __restrict__ out, int n, int d, float inv_n)
{
    __shared__ float s_cand[CAND_CAP];
    __shared__ float s_red[NWAVES];
    __shared__ int   s_cnt;
    __shared__ float s_bcast;

    const int row  = blockIdx.x;
    const int t    = threadIdx.x;
    const int lane = t & 63;
    const int wave = t >> 6;
    const float* __restrict__ xr = x + (size_t)row * (size_t)d;

    if (t == 0) s_cnt = 0;

    // ---- single HBM pass: row -> registers ----
    float4 r[8];
#pragma unroll
    for (int i = 0; i < 8; ++i) {
        int e = (i * BLOCK + t) * 4;
        if (e + 4 <= d) {
            r[i] = *reinterpret_cast<const float4*>(xr + e);
        } else {
            float4 v = make_float4(-INFINITY, -INFINITY, -INFINITY, -INFINITY);
            if (e < d)     v.x = xr[e];
            if (e + 1 < d) v.y = xr[e + 1];
            if (e + 2 < d) v.z = xr[e + 2];
            r[i] = v;
        }
    }

    // ---- block max ----
    float m = -INFINITY;
#pragma unroll
    for (int i = 0; i < 8; ++i)
        m = fmaxf(m, fmaxf(fmaxf(r[i].x, r[i].y), fmaxf(r[i].z, r[i].w)));
    m = waveReduceMax(m);
    if (lane == 0) s_red[wave] = m;
    __syncthreads();
    if (wave == 0) {
        float v = (lane < NWAVES) ? s_red[lane] : -INFINITY;
        v = waveReduceMax(v);
        if (lane == 0) s_bcast = v;
    }
    __syncthreads();
    const float rowmax = s_bcast;

    // ---- candidate filter via per-wave ballot compaction ----
    const float thr = rowmax - 2.0f;
#pragma unroll
    for (int i = 0; i < 8; ++i) {
        float vals[4] = { r[i].x, r[i].y, r[i].z, r[i].w };
#pragma unroll
        for (int c = 0; c < 4; ++c) {
            float v = vals[c];
            bool pred = (v >= thr);
            unsigned long long mask = __ballot(pred);
            if (mask) {                              // wave-uniform branch
                int base;
                if (lane == 0) base = atomicAdd(&s_cnt, __popcll(mask));
                base = __shfl(base, 0, 64);
                if (pred) {
                    int pos = base + (int)__popcll(mask & ((1ull << lane) - 1ull));
                    if (pos < CAND_CAP) s_cand[pos] = (v - rowmax) * 0.5f;
                }
            }
        }
    }
    __syncthreads();

    // ---- wave 0: register-resident root-find + loss terms ----
    if (wave == 0) {
        const int k = min(s_cnt, CAND_CAP);

        float ur[NREG];
#pragma unroll
        for (int j = 0; j < NREG; ++j) {
            int idx = lane + 64 * j;
            ur[j] = (idx < k) ? s_cand[idx] : -1e30f;   // sentinel: never in support
        }

        // bisection: f monotone decreasing, f(-1)>=1>=f(0), tau* in [-1,0]
        float lo = -1.0f, hi = 0.0f;
        for (int it = 0; it < 18; ++it) {
            float tau = 0.5f * (lo + hi);
            float acc = 0.0f;
#pragma unroll
            for (int j = 0; j < NREG; ++j) {
                float u = ur[j] - tau;
                acc += (u > 0.0f) ? u * u : 0.0f;
            }
            for (int j = 64 * NREG + lane; j < k; j += 64) {  // overflow tail (normally 0-trip)
                float u = s_cand[j] - tau;
                if (u > 0.0f) acc += u * u;
            }
            float tot = waveReduceSum(acc);
            tot = __shfl(tot, 0, 64);
            if (tot >= 1.0f) lo = tau; else hi = tau;
        }
        const float tau_b = 0.5f * (lo + hi);

        // exact closed form on identified support: tau* = mean - sqrt((1-ss)/k)
        float s1 = 0.0f, s2 = 0.0f, sc = 0.0f;
#pragma unroll
        for (int j = 0; j < NREG; ++j) {
            float u = ur[j];
            if (u > tau_b) { s1 += u; s2 += u * u; sc += 1.0f; }
        }
        for (int j = 64 * NREG + lane; j < k; j += 64) {
            float u = s_cand[j];
            if (u > tau_b) { s1 += u; s2 += u * u; sc += 1.0f; }
        }
        s1 = waveReduceSum(s1); s1 = __shfl(s1, 0, 64);
        s2 = waveReduceSum(s2); s2 = __shfl(s2, 0, 64);
        sc = waveReduceSum(sc); sc = __shfl(sc, 0, 64);
        float mean  = s1 / sc;
        float ss    = s2 - s1 * mean;              // sum of squared deviations
        float delta = (1.0f - ss) / sc;
        if (delta < 0.0f) delta = 0.0f;
        const float tau_star = mean - sqrtf(delta);

        // loss terms: sum p^{3/2} = sum u^3;  dot(p, x) with x = 2u + rowmax
        float p32 = 0.0f, dot = 0.0f;
#pragma unroll
        for (int j = 0; j < NREG; ++j) {
            float u = ur[j] - tau_star;
            if (u > 0.0f) {
                float p = u * u;
                p32 += p * u;
                dot += p * (2.0f * ur[j] + rowmax);
            }
        }
        for (int j = 64 * NREG + lane; j < k; j += 64) {
            float uc = s_cand[j];
            float u  = uc - tau_star;
            if (u > 0.0f) {
                float p = u * u;
                p32 += p * u;
                dot += p * (2.0f * uc + rowmax);
            }
        }
        p32 = waveReduceSum(p32);
        dot = waveReduceSum(dot);
        if (lane == 0) {
            float xt   = xr[tgt[row]];
            float loss = (1.0f - p32) * (4.0f / 3.0f) + dot - xt;
            atomicAdd(out, loss * inv_n);
        }
    }
}

extern "C" void kernel_launch(void* const* d_in, const int* in_sizes, int n_in,
                              void* d_out, int out_size, void* d_ws, size_t ws_size,
                              hipStream_t stream) {
    const float* x   = (const float*)d_in[0];
    const int*   tgt = (const int*)d_in[1];
    float*       out = (float*)d_out;

    const int n = in_sizes[1];
    const int d = in_sizes[0] / n;

    hipMemsetAsync(out, 0, (size_t)out_size * sizeof(float), stream);
    tsallis15_kernel<<<n, BLOCK, 0, stream>>>(x, tgt, out, n, d, 1.0f / (float)n);
}